// Round 4
// baseline (170.837 us; speedup 1.0000x reference)
//
#include <hip/hip_runtime.h>
#include <hip/hip_bf16.h>

// y[b, c] = (sum_k x[b,k] * W[c % 512, k]) + bias[c]
// R4: (1) one streaming pass converts x,W fp32->bf16 into d_ws (needs 36 MB);
//     (2) GEMM: 64x64 output tiles, full K=4096, NO split-K -> epilogue writes
//         final acc+bias into all 8 column copies (combine kernel deleted);
//     (3) bf16 LDS tiles (16 KB/buffer, dbuf 32 KB/block -> 5 blocks/CU LDS cap,
//         all 512 blocks resident) staged via global_load_lds DMA with
//         global-side XOR chunk swizzle (conflict-free 16-lane read phases).

typedef __bf16 bf8 __attribute__((ext_vector_type(8)));
typedef float f4 __attribute__((ext_vector_type(4)));
typedef unsigned int uint;
typedef unsigned short ushort;

constexpr int M = 4096;
constexpr int K = 4096;
constexpr int NS = 512;          // shared rows (small-GEMM N)
constexpr int OUTF = 4096;       // output columns (8 copies of NS)
constexpr int BM = 64, BN = 64, BK = 64;
constexpr int NITER = K / BK;    // 64

#define PERM_HI2(hi, lo) __builtin_amdgcn_perm((hi), (lo), 0x07060302u)

__device__ __forceinline__ void async16(const ushort* g, ushort* l) {
  __builtin_amdgcn_global_load_lds(
      (const __attribute__((address_space(1))) void*)g,
      (__attribute__((address_space(3))) void*)l, 16, 0, 0);
}

// fp32 -> bf16 (truncate), 8 elems/thread, covers x then W exactly.
__global__ __launch_bounds__(256)
void convert_kernel(const float* __restrict__ x, const float* __restrict__ w,
                    ushort* __restrict__ xb, ushort* __restrict__ wb) {
  const size_t i = (size_t)blockIdx.x * 256 + threadIdx.x;   // 16B-out chunk id
  constexpr size_t NX = (size_t)M * K / 8;                   // 2M x-chunks
  const float* src;
  ushort* dst;
  if (i < NX) { src = x + i * 8; dst = xb + i * 8; }
  else        { const size_t j = i - NX; src = w + j * 8; dst = wb + j * 8; }
  const uint4 a = *reinterpret_cast<const uint4*>(src);
  const uint4 b = *reinterpret_cast<const uint4*>(src + 4);
  uint4 o;
  o.x = PERM_HI2(a.y, a.x); o.y = PERM_HI2(a.w, a.z);
  o.z = PERM_HI2(b.y, b.x); o.w = PERM_HI2(b.w, b.z);
  *reinterpret_cast<uint4*>(dst) = o;
}

__global__ __launch_bounds__(256, 5)
void gemm_kernel(const ushort* __restrict__ xb, const ushort* __restrict__ wb,
                 const float* __restrict__ bias, float* __restrict__ out) {
  __shared__ __align__(16) ushort As[2][BM * BK];   // 8 KB per buffer
  __shared__ __align__(16) ushort Bs[2][BN * BK];

  const int gid = blockIdx.x;      // 512 blocks
  const int nt = gid & 7;          // 8 N tiles fastest -> x slab reused by
  const int mt = gid >> 3;         // consecutive blocks (L2); W fits L2 whole.

  const int tid  = threadIdx.x;
  const int wv   = tid >> 6;
  const int lane = tid & 63;

  // --- DMA staging: tile = 64 rows x 64 bf16 = 512 16B-chunks.
  // LDS chunk c holds global chunk ((c&7) ^ (row&7)) of row (c>>3).
  // Wave wv slot j covers LDS chunks (wv*2+j)*64 + lane.
  int goff[2], lloc[2];
#pragma unroll
  for (int j = 0; j < 2; ++j) {
    const int c = (wv * 2 + j) * 64 + lane;
    const int r = c >> 3;
    const int g = (c & 7) ^ (r & 7);
    goff[j] = r * K + g * 8;            // ushort offset from tile base
    lloc[j] = (wv * 2 + j) * 512;       // wave-uniform slot base (ushorts)
  }

  const ushort* xT = xb + (size_t)(mt * BM) * K;
  const ushort* wT = wb + (size_t)(nt * BN) * K;

  // --- fragment decode (16x16x32 bf16, proven layout) ---
  const int wm = (wv & 1) * 32;        // wave M origin in tile
  const int wn = (wv >> 1) * 32;       // wave N origin in tile
  const int lr = lane & 15;
  const int lq = lane >> 4;

  f4 acc[2][2] = {};

  // prologue: tile 0 -> buffer 0
#pragma unroll
  for (int j = 0; j < 2; ++j) {
    async16(xT + goff[j], &As[0][lloc[j]]);
    async16(wT + goff[j], &Bs[0][lloc[j]]);
  }
  __syncthreads();

  for (int kk = 0; kk < NITER; ++kk) {
    const int cur = kk & 1;

    if (kk + 1 < NITER) {
      const int ko = (kk + 1) * BK;
#pragma unroll
      for (int j = 0; j < 2; ++j) {
        async16(xT + ko + goff[j], &As[cur ^ 1][lloc[j]]);
        async16(wT + ko + goff[j], &Bs[cur ^ 1][lloc[j]]);
      }
    }

#pragma unroll
    for (int t = 0; t < 2; ++t) {
      const int sc = ((t * 4 + lq) ^ (lr & 7)) * 8;   // swizzled chunk offset
      bf8 af[2], bfv[2];
#pragma unroll
      for (int mf = 0; mf < 2; ++mf)
        af[mf] = *reinterpret_cast<const bf8*>(&As[cur][(wm + mf * 16 + lr) * BK + sc]);
#pragma unroll
      for (int nf = 0; nf < 2; ++nf)
        bfv[nf] = *reinterpret_cast<const bf8*>(&Bs[cur][(wn + nf * 16 + lr) * BK + sc]);
#pragma unroll
      for (int mf = 0; mf < 2; ++mf)
#pragma unroll
        for (int nf = 0; nf < 2; ++nf)
          acc[mf][nf] = __builtin_amdgcn_mfma_f32_16x16x32_bf16(af[mf], bfv[nf], acc[mf][nf], 0, 0, 0);
    }

    __syncthreads();
  }

  // --- epilogue: final y = acc + bias into all 8 column copies ---
  float bv[8][2];
#pragma unroll
  for (int rep = 0; rep < 8; ++rep)
#pragma unroll
    for (int nf = 0; nf < 2; ++nf)
      bv[rep][nf] = bias[rep * NS + nt * BN + wn + nf * 16 + lr];

  float* ob = out + (size_t)(mt * BM) * OUTF;
#pragma unroll
  for (int mf = 0; mf < 2; ++mf)
#pragma unroll
    for (int r = 0; r < 4; ++r) {
      const int row = wm + mf * 16 + lq * 4 + r;
#pragma unroll
      for (int nf = 0; nf < 2; ++nf) {
        const float v = acc[mf][nf][r];
        const int col0 = nt * BN + wn + nf * 16 + lr;
#pragma unroll
        for (int rep = 0; rep < 8; ++rep)
          ob[(size_t)row * OUTF + rep * NS + col0] = v + bv[rep][nf];
      }
    }
}

extern "C" void kernel_launch(void* const* d_in, const int* in_sizes, int n_in,
                              void* d_out, int out_size, void* d_ws, size_t ws_size,
                              hipStream_t stream) {
  (void)in_sizes; (void)n_in; (void)out_size; (void)ws_size;
  const float* x    = (const float*)d_in[0];
  const float* w    = (const float*)d_in[1];
  const float* bias = (const float*)d_in[2];
  float* out = (float*)d_out;

  ushort* xb = (ushort*)d_ws;                       // 32 MB bf16 x
  ushort* wb = (ushort*)d_ws + (size_t)M * K;       // 4 MB bf16 W (ws >= 36 MB)

  constexpr int conv_blocks = (int)(((size_t)M * K / 8 + (size_t)NS * K / 8) / 256); // 9216
  convert_kernel<<<dim3(conv_blocks), dim3(256), 0, stream>>>(x, w, xb, wb);
  gemm_kernel<<<dim3(64 * 8), dim3(256), 0, stream>>>(xb, wb, bias, out);
}

// Round 5
// 162.647 us; speedup vs baseline: 1.0504x; 1.0504x over previous
//
#include <hip/hip_runtime.h>
#include <hip/hip_bf16.h>

// y[b, c] = (sum_k x[b,k] * W[c % 512, k]) + bias[c]
// R5: convert x,W fp32->bf16 into d_ws; GEMM 64x64 tiles, full K, no split-K.
// K-loop = 3-stage LDS ring, raw s_barrier + fine-grained s_waitcnt vmcnt(4)
// (never vmcnt(0) until the last tile) so global_load_lds DMA issued 2 full
// iterations ahead stays in flight across barriers (hipBLASLt-style pipeline).
// XCD-aware block swizzle: blockIdx&7 == mt&7 -> all 8 nt-blocks of an x-slab
// run on one XCD (x slab fetched once). Epilogue: LDS transpose -> float4
// stores of acc+bias into all 8 column copies.

typedef __bf16 bf8 __attribute__((ext_vector_type(8)));
typedef float f4 __attribute__((ext_vector_type(4)));
typedef unsigned int uint;
typedef unsigned short ushort;

constexpr int M = 4096;
constexpr int K = 4096;
constexpr int NS = 512;
constexpr int OUTF = 4096;
constexpr int BM = 64, BN = 64, BK = 64;
constexpr int NITER = K / BK;    // 64
constexpr int SSTR = 68;         // epilogue scratch stride (floats); 272B = 17*16 keeps 16B align

#define PERM_HI2(hi, lo) __builtin_amdgcn_perm((hi), (lo), 0x07060302u)
// s_waitcnt imm: vmcnt[3:0]|expcnt[6:4]|lgkmcnt[11:8]|vmcnt[15:14]
#define WAITCNT_VM4 0xF74   // vmcnt<=4, expcnt/lgkmcnt unconstrained
#define WAITCNT_VM0 0xF70   // vmcnt<=0

__device__ __forceinline__ void async16(const ushort* g, ushort* l) {
  __builtin_amdgcn_global_load_lds(
      (const __attribute__((address_space(1))) void*)g,
      (__attribute__((address_space(3))) void*)l, 16, 0, 0);
}

// fp32 -> bf16 (truncate), 8 elems/thread; covers x then W exactly.
__global__ __launch_bounds__(256)
void convert_kernel(const float* __restrict__ x, const float* __restrict__ w,
                    ushort* __restrict__ xb, ushort* __restrict__ wb) {
  const size_t i = (size_t)blockIdx.x * 256 + threadIdx.x;
  constexpr size_t NX = (size_t)M * K / 8;
  const float* src;
  ushort* dst;
  if (i < NX) { src = x + i * 8; dst = xb + i * 8; }
  else        { const size_t j = i - NX; src = w + j * 8; dst = wb + j * 8; }
  const uint4 a = *reinterpret_cast<const uint4*>(src);
  const uint4 b = *reinterpret_cast<const uint4*>(src + 4);
  uint4 o;
  o.x = PERM_HI2(a.y, a.x); o.y = PERM_HI2(a.w, a.z);
  o.z = PERM_HI2(b.y, b.x); o.w = PERM_HI2(b.w, b.z);
  *reinterpret_cast<uint4*>(dst) = o;
}

__global__ __launch_bounds__(256, 2)
void gemm_kernel(const ushort* __restrict__ xb, const ushort* __restrict__ wb,
                 const float* __restrict__ bias, float* __restrict__ out) {
  __shared__ __align__(16) ushort As[3][BM * BK];   // 3-stage ring, 8 KB/stage
  __shared__ __align__(16) ushort Bs[3][BN * BK];

  // XCD swizzle: blockIdx&7 = mt&7 -> same-slab blocks share an XCD.
  const int b  = blockIdx.x;                  // 512 blocks
  const int mt = ((b >> 6) << 3) | (b & 7);   // 0..63
  const int nt = (b >> 3) & 7;                // 0..7

  const int tid  = threadIdx.x;
  const int wv   = tid >> 6;
  const int lane = tid & 63;

  // DMA staging: tile = 64 rows x 64 bf16 = 512 16B-chunks.
  // LDS chunk c holds global chunk ((c&7) ^ (row&7)) of row (c>>3).
  int goff[2], lloc[2];
#pragma unroll
  for (int j = 0; j < 2; ++j) {
    const int c = (wv * 2 + j) * 64 + lane;
    const int r = c >> 3;
    const int g = (c & 7) ^ (r & 7);
    goff[j] = r * K + g * 8;
    lloc[j] = (wv * 2 + j) * 512;
  }

  const ushort* xT = xb + (size_t)(mt * BM) * K;
  const ushort* wT = wb + (size_t)(nt * BN) * K;

  const int wm = (wv & 1) * 32;
  const int wn = (wv >> 1) * 32;
  const int lr = lane & 15;
  const int lq = lane >> 4;

  f4 acc[2][2] = {};

  auto issue = [&](int tile, int stage) {
    const int ko = tile * BK;
#pragma unroll
    for (int j = 0; j < 2; ++j) {
      async16(xT + ko + goff[j], &As[stage][lloc[j]]);
      async16(wT + ko + goff[j], &Bs[stage][lloc[j]]);
    }
  };

  // prologue: tiles 0,1 into stages 0,1
  issue(0, 0);
  issue(1, 1);

  int st = 0;                 // stage of current tile kk
  for (int kk = 0; kk < NITER; ++kk) {
    // wait for this wave's oldest 4 DMAs (tile kk); tile kk+1 stays in flight
    if (kk + 1 < NITER) __builtin_amdgcn_s_waitcnt(WAITCNT_VM4);
    else                __builtin_amdgcn_s_waitcnt(WAITCNT_VM0);
    __builtin_amdgcn_s_barrier();    // publish tile kk; all waves done reading stage (kk-1)%3
    asm volatile("" ::: "memory");

    // issue tile kk+2 into stage (kk+2)%3 == (kk-1)%3 (safe: post-barrier)
    if (kk + 2 < NITER) {
      int st2 = st + 2; if (st2 >= 3) st2 -= 3;
      issue(kk + 2, st2);
    }

    const ushort* aT = As[st];
    const ushort* bT = Bs[st];
#pragma unroll
    for (int t = 0; t < 2; ++t) {
      const int sc = ((t * 4 + lq) ^ (lr & 7)) * 8;
      bf8 af[2], bfv[2];
#pragma unroll
      for (int mf = 0; mf < 2; ++mf)
        af[mf] = *reinterpret_cast<const bf8*>(&aT[(wm + mf * 16 + lr) * BK + sc]);
#pragma unroll
      for (int nf = 0; nf < 2; ++nf)
        bfv[nf] = *reinterpret_cast<const bf8*>(&bT[(wn + nf * 16 + lr) * BK + sc]);
#pragma unroll
      for (int mf = 0; mf < 2; ++mf)
#pragma unroll
        for (int nf = 0; nf < 2; ++nf)
          acc[mf][nf] = __builtin_amdgcn_mfma_f32_16x16x32_bf16(af[mf], bfv[nf], acc[mf][nf], 0, 0, 0);
    }
    asm volatile("" ::: "memory");

    if (++st >= 3) st = 0;
  }

  // ---- epilogue: LDS transpose -> float4 stores into all 8 column copies ----
  __syncthreads();
  float* sc = reinterpret_cast<float*>(&As[0][0]);   // 24 KB >= 64*68*4 B
#pragma unroll
  for (int mf = 0; mf < 2; ++mf)
#pragma unroll
    for (int nf = 0; nf < 2; ++nf)
#pragma unroll
      for (int r = 0; r < 4; ++r)
        sc[(wm + mf * 16 + lq * 4 + r) * SSTR + wn + nf * 16 + lr] = acc[mf][nf][r];
  __syncthreads();

  const int c4 = tid & 15;          // float4 column within tile
  const int r0 = (tid >> 4) * 4;    // 4 rows per thread
  const float4* bias4 = reinterpret_cast<const float4*>(bias);
  float4 bb[8];
#pragma unroll
  for (int rep = 0; rep < 8; ++rep)
    bb[rep] = bias4[rep * 128 + nt * 16 + c4];

#pragma unroll
  for (int rr = 0; rr < 4; ++rr) {
    const int row = r0 + rr;
    const float4 v = *reinterpret_cast<const float4*>(&sc[row * SSTR + c4 * 4]);
    float* orow = out + (size_t)(mt * BM + row) * OUTF + nt * BN + c4 * 4;
#pragma unroll
    for (int rep = 0; rep < 8; ++rep) {
      float4 o;
      o.x = v.x + bb[rep].x; o.y = v.y + bb[rep].y;
      o.z = v.z + bb[rep].z; o.w = v.w + bb[rep].w;
      *reinterpret_cast<float4*>(orow + rep * NS) = o;
    }
  }
}

extern "C" void kernel_launch(void* const* d_in, const int* in_sizes, int n_in,
                              void* d_out, int out_size, void* d_ws, size_t ws_size,
                              hipStream_t stream) {
  (void)in_sizes; (void)n_in; (void)out_size; (void)ws_size;
  const float* x    = (const float*)d_in[0];
  const float* w    = (const float*)d_in[1];
  const float* bias = (const float*)d_in[2];
  float* out = (float*)d_out;

  ushort* xb = (ushort*)d_ws;                       // 32 MB bf16 x
  ushort* wb = (ushort*)d_ws + (size_t)M * K;       // 4 MB bf16 W (ws >= 36 MB)

  constexpr int conv_blocks = (int)(((size_t)M * K / 8 + (size_t)NS * K / 8) / 256); // 9216
  convert_kernel<<<dim3(conv_blocks), dim3(256), 0, stream>>>(x, w, xb, wb);
  gemm_kernel<<<dim3(64 * 8), dim3(256), 0, stream>>>(xb, wb, bias, out);
}